// Round 9
// baseline (331.189 us; speedup 1.0000x reference)
//
#include <hip/hip_runtime.h>
#include <hip/hip_fp16.h>

static __device__ __forceinline__ float gelu(float x) {
    return 0.5f * x * (1.0f + erff(x * 0.70710678118654752f));
}

#define NBE 64    // nodes per block, encode part (32 rows x 2 nodes)
#define NBN 64    // nodes per block, k_node (32 rows x 2 nodes) -> grid 1024
#define SN  68    // k_node LDS row stride (floats), 16B aligned
#define CAP 64    // CSR slot capacity per node

static __device__ __forceinline__ void acc8(float* a, uint4 u) {
    float2 f0 = __half22float2(*(__half2*)&u.x);
    float2 f1 = __half22float2(*(__half2*)&u.y);
    float2 f2 = __half22float2(*(__half2*)&u.z);
    float2 f3 = __half22float2(*(__half2*)&u.w);
    a[0] += f0.x; a[1] += f0.y; a[2] += f1.x; a[3] += f1.y;
    a[4] += f2.x; a[5] += f2.y; a[6] += f3.x; a[7] += f3.y;
}

static __device__ __forceinline__ uint4 pack8(const float* v) {
    __half2 p0 = __floats2half2_rn(v[0], v[1]);
    __half2 p1 = __floats2half2_rn(v[2], v[3]);
    __half2 p2 = __floats2half2_rn(v[4], v[5]);
    __half2 p3 = __floats2half2_rn(v[6], v[7]);
    uint4 u;
    u.x = *(unsigned*)&p0; u.y = *(unsigned*)&p1;
    u.z = *(unsigned*)&p2; u.w = *(unsigned*)&p3;
    return u;
}

// ---- merged: encoder (blocks < encB) + slot-scatter (blocks >= encB) ----
__global__ void __launch_bounds__(256, 1)
k_enc_scat(const float* __restrict__ x,
           const float* __restrict__ grid,
           const float* __restrict__ W1,
           const float* __restrict__ b1,
           const float* __restrict__ W2,
           const float* __restrict__ b2,
           const int* __restrict__ ei, int* __restrict__ cnt,
           int* __restrict__ ssrc,
           __half* __restrict__ h16, int N, int E, int encB)
{
    __shared__ float sx[NBE * 10];
    __shared__ float sg[NBE * 2];
    __shared__ float sm[NBE * 132];
    int tid = threadIdx.x;
    if ((int)blockIdx.x >= encB) {
        int e4 = (blockIdx.x - encB) * 256 + tid;   // 4 edges per thread
        if (e4 * 4 < E) {
            const int4* s4 = (const int4*)ei;
            const int4* d4 = (const int4*)(ei + E);
            int4 s = s4[e4];
            int4 d = d4[e4];
            int p;
            p = atomicAdd(&cnt[d.x], 1); if (p < CAP) ssrc[((size_t)d.x << 6) + p] = s.x;
            p = atomicAdd(&cnt[d.y], 1); if (p < CAP) ssrc[((size_t)d.y << 6) + p] = s.y;
            p = atomicAdd(&cnt[d.z], 1); if (p < CAP) ssrc[((size_t)d.z << 6) + p] = s.z;
            p = atomicAdd(&cnt[d.w], 1); if (p < CAP) ssrc[((size_t)d.w << 6) + p] = s.w;
        }
        return;
    }
    int n0 = blockIdx.x * NBE;
    for (int i = tid; i < NBE * 10; i += 256) sx[i] = x[(size_t)n0 * 10 + i];
    if (tid < NBE * 2) sg[tid] = grid[(size_t)n0 * 2 + tid];
    __syncthreads();

    int l = tid & 7, r = tid >> 3;      // r in [0,32)
    int mb = 16 * l;
    float in[2][12];
#pragma unroll
    for (int m = 0; m < 2; m++) {
        int node = r + 32 * m;
#pragma unroll
        for (int k = 0; k < 10; k++) in[m][k] = sx[node * 10 + k];
        in[m][10] = sg[node * 2 + 0];
        in[m][11] = sg[node * 2 + 1];
    }

    float macc[2][16];
#pragma unroll
    for (int i = 0; i < 16; i++) {
        float b = b1[mb + i];
        macc[0][i] = b; macc[1][i] = b;
    }
#pragma unroll
    for (int k = 0; k < 12; k++) {
        const float4* w = (const float4*)(W1 + k * 128 + mb);
#pragma unroll
        for (int q = 0; q < 4; q++) {
            float4 wv = w[q];
#pragma unroll
            for (int m = 0; m < 2; m++) {
                float xv = in[m][k];
                macc[m][4 * q + 0] += xv * wv.x;
                macc[m][4 * q + 1] += xv * wv.y;
                macc[m][4 * q + 2] += xv * wv.z;
                macc[m][4 * q + 3] += xv * wv.w;
            }
        }
    }
#pragma unroll
    for (int m = 0; m < 2; m++) {
        float4* smp = (float4*)(sm + (r + 32 * m) * 132 + mb);
#pragma unroll
        for (int q = 0; q < 4; q++)
            smp[q] = make_float4(gelu(macc[m][4 * q]), gelu(macc[m][4 * q + 1]),
                                 gelu(macc[m][4 * q + 2]), gelu(macc[m][4 * q + 3]));
    }
    __syncthreads();

    int ob = 8 * l;
    float out8[2][8];
#pragma unroll
    for (int j = 0; j < 8; j++) {
        float b = b2[ob + j];
        out8[0][j] = b; out8[1][j] = b;
    }
#pragma unroll 2
    for (int i4 = 0; i4 < 128; i4 += 4) {
        float mva[2][4];
#pragma unroll
        for (int m = 0; m < 2; m++)
            *(float4*)mva[m] = *(const float4*)&sm[(r + 32 * m) * 132 + i4];
#pragma unroll
        for (int ii = 0; ii < 4; ii++) {
            const float4* w = (const float4*)(W2 + (i4 + ii) * 64 + ob);
            float4 w0 = w[0], w1 = w[1];
#pragma unroll
            for (int m = 0; m < 2; m++) {
                float mv = mva[m][ii];
                out8[m][0] += mv * w0.x; out8[m][1] += mv * w0.y;
                out8[m][2] += mv * w0.z; out8[m][3] += mv * w0.w;
                out8[m][4] += mv * w1.x; out8[m][5] += mv * w1.y;
                out8[m][6] += mv * w1.z; out8[m][7] += mv * w1.w;
            }
        }
    }
#pragma unroll
    for (int m = 0; m < 2; m++)
        ((uint4*)(h16 + (size_t)(n0 + r + 32 * m) * 64))[l] = pack8(out8[m]);
}

// ---- gather per-node sums from CAP-slot CSR: 4-way independent load chains ----
// 8 lanes/node; lane owns 8 h-dims read as one uint4 (8 halves): 128B/edge.
__global__ void k_gather(const __half* __restrict__ h16,
                         const float* __restrict__ grid,
                         const int* __restrict__ ssrc, const int* __restrict__ cnt,
                         __half* __restrict__ sum_h16, float* __restrict__ sum_g,
                         float* __restrict__ sum_d, int N)
{
    int tid = blockIdx.x * blockDim.x + threadIdx.x;
    int n = tid >> 3;
    int l = tid & 7;
    if (n >= N) return;
    int beg = n << 6;
    int dg = min(cnt[n], CAP);
    const uint4* h8 = (const uint4*)h16;
    float a0[8] = {0,0,0,0,0,0,0,0};
    float a1[8] = {0,0,0,0,0,0,0,0};
    float a2[8] = {0,0,0,0,0,0,0,0};
    float a3[8] = {0,0,0,0,0,0,0,0};
    float sgx = 0.f, sgy = 0.f, sd = 0.f, gix = 0.f, giy = 0.f;
    if (l == 0) { gix = grid[2 * n]; giy = grid[2 * n + 1]; }
    int i = 0;
    for (; i + 3 < dg; i += 4) {
        int4 s = *(const int4*)&ssrc[beg + i];   // 256B-aligned CSR row
        uint4 u0 = h8[(size_t)s.x * 8 + l];
        uint4 u1 = h8[(size_t)s.y * 8 + l];
        uint4 u2 = h8[(size_t)s.z * 8 + l];
        uint4 u3 = h8[(size_t)s.w * 8 + l];
        acc8(a0, u0); acc8(a1, u1); acc8(a2, u2); acc8(a3, u3);
        if (l == 0) {
            float gx0 = grid[2 * s.x], gy0 = grid[2 * s.x + 1];
            float gx1 = grid[2 * s.y], gy1 = grid[2 * s.y + 1];
            float gx2 = grid[2 * s.z], gy2 = grid[2 * s.z + 1];
            float gx3 = grid[2 * s.w], gy3 = grid[2 * s.w + 1];
            float dx0 = gix - gx0, dy0 = giy - gy0;
            float dx1 = gix - gx1, dy1 = giy - gy1;
            float dx2 = gix - gx2, dy2 = giy - gy2;
            float dx3 = gix - gx3, dy3 = giy - gy3;
            sd += sqrtf(dx0 * dx0 + dy0 * dy0) + sqrtf(dx1 * dx1 + dy1 * dy1)
                + sqrtf(dx2 * dx2 + dy2 * dy2) + sqrtf(dx3 * dx3 + dy3 * dy3);
            sgx += gx0 + gx1 + gx2 + gx3;
            sgy += gy0 + gy1 + gy2 + gy3;
        }
    }
    for (; i < dg; i++) {
        int s0 = ssrc[beg + i];
        uint4 u0 = h8[(size_t)s0 * 8 + l];
        acc8(a0, u0);
        if (l == 0) {
            float gx0 = grid[2 * s0], gy0 = grid[2 * s0 + 1];
            float dx0 = gix - gx0, dy0 = giy - gy0;
            sd += sqrtf(dx0 * dx0 + dy0 * dy0);
            sgx += gx0; sgy += gy0;
        }
    }
#pragma unroll
    for (int j = 0; j < 8; j++) a0[j] += a1[j] + a2[j] + a3[j];
    ((uint4*)(sum_h16 + (size_t)n * 64))[l] = pack8(a0);
    if (l == 0) { sum_d[n] = sd; sum_g[2 * n] = sgx; sum_g[2 * n + 1] = sgy; }
}

// ---- node update + decoder, fused. 8 lanes x 32 rows, M=2 nodes/thread ----
// fp32 LDS tiles (34.8 KB total), grid 1024 -> 4 blocks/CU, 16 waves/CU.
__global__ void __launch_bounds__(256, 1)
k_node(const __half* __restrict__ h16, const __half* __restrict__ sum_h16,
       const float* __restrict__ sum_g, const float* __restrict__ sum_d,
       const int* __restrict__ cnt, const float* __restrict__ grid,
       const float* __restrict__ Wk, const float* __restrict__ bk,
       const float* __restrict__ Ww, const float* __restrict__ bw,
       const float* __restrict__ Wd1, const float* __restrict__ bd1,
       const float* __restrict__ Wd2, const float* __restrict__ bd2,
       float* __restrict__ out, int N)
{
    __shared__ float shh[NBN * SN];
    __shared__ float shs[NBN * SN];
    int tid = threadIdx.x;
    int n0 = blockIdx.x * NBN;
    // stage h and sum_h (fp16 -> fp32 once), coalesced
    const uint4* hg = (const uint4*)(h16 + (size_t)n0 * 64);
    const uint4* sg8 = (const uint4*)(sum_h16 + (size_t)n0 * 64);
    for (int j = tid; j < NBN * 8; j += 256) {
        int m = j >> 3, q = j & 7;
        uint4 u = hg[j];
        float2 f0 = __half22float2(*(__half2*)&u.x);
        float2 f1 = __half22float2(*(__half2*)&u.y);
        float2 f2 = __half22float2(*(__half2*)&u.z);
        float2 f3 = __half22float2(*(__half2*)&u.w);
        float* d = &shh[m * SN + q * 8];
        *(float4*)&d[0] = make_float4(f0.x, f0.y, f1.x, f1.y);
        *(float4*)&d[4] = make_float4(f2.x, f2.y, f3.x, f3.y);
        u = sg8[j];
        f0 = __half22float2(*(__half2*)&u.x);
        f1 = __half22float2(*(__half2*)&u.y);
        f2 = __half22float2(*(__half2*)&u.z);
        f3 = __half22float2(*(__half2*)&u.w);
        d = &shs[m * SN + q * 8];
        *(float4*)&d[0] = make_float4(f0.x, f0.y, f1.x, f1.y);
        *(float4*)&d[4] = make_float4(f2.x, f2.y, f3.x, f3.y);
    }
    __syncthreads();

    int l = tid & 7, r = tid >> 3;
    int ob = 8 * l;
    float deg[2], sd[2], sgx[2], sgy[2], gix[2], giy[2];
#pragma unroll
    for (int m = 0; m < 2; m++) {
        int n = n0 + r + 32 * m;
        float dg = (float)cnt[n];
        deg[m] = dg;
        sd[m] = sum_d[n];
        sgx[m] = sum_g[2 * n]; sgy[m] = sum_g[2 * n + 1];
        gix[m] = grid[2 * n] * dg; giy[m] = grid[2 * n + 1] * dg;
    }
    float acc[2][8];
#pragma unroll
    for (int j = 0; j < 8; j++) {
        int o = ob + j;
        float a0 = bw[o], a1 = bk[o], a2 = Wk[o], a3 = Wk[64 + o],
              a4 = Wk[128 + o], a5 = Wk[192 + o], a6 = Wk[256 + o];
#pragma unroll
        for (int m = 0; m < 2; m++)
            acc[m][j] = a0 + deg[m] * a1 + sd[m] * a2 + gix[m] * a3
                      + giy[m] * a4 + sgx[m] * a5 + sgy[m] * a6;
    }

#pragma unroll 2
    for (int k4 = 0; k4 < 64; k4 += 4) {
        float hva[2][4], sva[2][4];
#pragma unroll
        for (int m = 0; m < 2; m++) {
            *(float4*)hva[m] = *(const float4*)&shh[(r + 32 * m) * SN + k4];
            *(float4*)sva[m] = *(const float4*)&shs[(r + 32 * m) * SN + k4];
        }
#pragma unroll
        for (int kk = 0; kk < 4; kk++) {
            int k = k4 + kk;
            const float4* ww = (const float4*)(Ww + k * 64 + ob);
            const float4* wc = (const float4*)(Wk + (size_t)(5 + k) * 64 + ob);
            const float4* wd = (const float4*)(Wk + (size_t)(69 + k) * 64 + ob);
            float4 w0 = ww[0], w1 = ww[1];
            float4 c0 = wc[0], c1 = wc[1];
            float4 d0 = wd[0], d1 = wd[1];
#pragma unroll
            for (int m = 0; m < 2; m++) {
                float hk = hva[m][kk], sk = sva[m][kk];
                float hd = deg[m] * hk;
                acc[m][0] += hk * w0.x + hd * c0.x + sk * d0.x;
                acc[m][1] += hk * w0.y + hd * c0.y + sk * d0.y;
                acc[m][2] += hk * w0.z + hd * c0.z + sk * d0.z;
                acc[m][3] += hk * w0.w + hd * c0.w + sk * d0.w;
                acc[m][4] += hk * w1.x + hd * c1.x + sk * d1.x;
                acc[m][5] += hk * w1.y + hd * c1.y + sk * d1.y;
                acc[m][6] += hk * w1.z + hd * c1.z + sk * d1.z;
                acc[m][7] += hk * w1.w + hd * c1.w + sk * d1.w;
            }
        }
    }
    __syncthreads();                 // done reading shh; reuse rows for h2
#pragma unroll
    for (int m = 0; m < 2; m++) {
        float* d = &shh[(r + 32 * m) * SN + ob];
        *(float4*)&d[0] = make_float4(gelu(acc[m][0]), gelu(acc[m][1]),
                                      gelu(acc[m][2]), gelu(acc[m][3]));
        *(float4*)&d[4] = make_float4(gelu(acc[m][4]), gelu(acc[m][5]),
                                      gelu(acc[m][6]), gelu(acc[m][7]));
    }
    __syncthreads();

    // decoder: 16 mids per thread x 2 nodes
    int mb = 16 * l;
    float macc[2][16];
#pragma unroll
    for (int i = 0; i < 16; i++) {
        float b = bd1[mb + i];
        macc[0][i] = b; macc[1][i] = b;
    }
#pragma unroll 2
    for (int o4 = 0; o4 < 64; o4 += 4) {
        float hva[2][4];
#pragma unroll
        for (int m = 0; m < 2; m++)
            *(float4*)hva[m] = *(const float4*)&shh[(r + 32 * m) * SN + o4];
#pragma unroll
        for (int oo = 0; oo < 4; oo++) {
            const float4* w = (const float4*)(Wd1 + (o4 + oo) * 128 + mb);
            float4 w0 = w[0], w1 = w[1], w2 = w[2], w3 = w[3];
#pragma unroll
            for (int m = 0; m < 2; m++) {
                float hv = hva[m][oo];
                macc[m][0]  += hv * w0.x; macc[m][1]  += hv * w0.y;
                macc[m][2]  += hv * w0.z; macc[m][3]  += hv * w0.w;
                macc[m][4]  += hv * w1.x; macc[m][5]  += hv * w1.y;
                macc[m][6]  += hv * w1.z; macc[m][7]  += hv * w1.w;
                macc[m][8]  += hv * w2.x; macc[m][9]  += hv * w2.y;
                macc[m][10] += hv * w2.z; macc[m][11] += hv * w2.w;
                macc[m][12] += hv * w3.x; macc[m][13] += hv * w3.y;
                macc[m][14] += hv * w3.z; macc[m][15] += hv * w3.w;
            }
        }
    }
    float pa[2] = {0.f, 0.f};
#pragma unroll
    for (int i = 0; i < 16; i++) {
        float wv = Wd2[mb + i];
        pa[0] += gelu(macc[0][i]) * wv;
        pa[1] += gelu(macc[1][i]) * wv;
    }
#pragma unroll
    for (int m = 0; m < 2; m++) {
        float p = pa[m];
        p += __shfl_xor(p, 1);
        p += __shfl_xor(p, 2);
        p += __shfl_xor(p, 4);
        if (l == 0) out[n0 + r + 32 * m] = p + bd2[0];
    }
}

extern "C" void kernel_launch(void* const* d_in, const int* in_sizes, int n_in,
                              void* d_out, int out_size, void* d_ws, size_t ws_size,
                              hipStream_t stream)
{
    const float* x    = (const float*)d_in[0];
    const float* grid = (const float*)d_in[1];
    const int*   ei   = (const int*)d_in[2];
    const float* W1   = (const float*)d_in[3];
    const float* b1   = (const float*)d_in[4];
    const float* W2   = (const float*)d_in[5];
    const float* b2   = (const float*)d_in[6];
    const float* Wk   = (const float*)d_in[7];
    const float* bk   = (const float*)d_in[8];
    const float* Ww   = (const float*)d_in[9];
    const float* bw   = (const float*)d_in[10];
    const float* Wd1  = (const float*)d_in[11];
    const float* bd1  = (const float*)d_in[12];
    const float* Wd2  = (const float*)d_in[13];
    const float* bd2  = (const float*)d_in[14];
    float* out = (float*)d_out;

    int N = in_sizes[0] / 10;
    int E = in_sizes[2] / 2;

    char* ws = (char*)d_ws;
    size_t o_h16  = 0;
    size_t o_sh16 = o_h16  + (size_t)N * 64 * 2;
    size_t o_sumg = o_sh16 + (size_t)N * 64 * 2;
    size_t o_sumd = o_sumg + (size_t)N * 2 * 4;
    size_t o_cnt  = o_sumd + (size_t)N * 4;
    size_t o_ssrc = o_cnt  + (size_t)N * 4;

    __half* h16     = (__half*)(ws + o_h16);
    __half* sum_h16 = (__half*)(ws + o_sh16);
    float* sum_g = (float*)(ws + o_sumg);
    float* sum_d = (float*)(ws + o_sumd);
    int*   cnt   = (int*)  (ws + o_cnt);
    int*   ssrc  = (int*)  (ws + o_ssrc);   // N * CAP ints

    hipMemsetAsync(cnt, 0, (size_t)N * 4, stream);

    int encB  = N / NBE;                 // 1024
    int scatB = (E / 4 + 255) / 256;     // 1024
    k_enc_scat<<<dim3(encB + scatB), dim3(256), 0, stream>>>(x, grid, W1, b1, W2, b2,
                                                             ei, cnt, ssrc, h16, N, E, encB);
    k_gather<<<dim3((N * 8 + 255) / 256), dim3(256), 0, stream>>>(h16, grid, ssrc, cnt,
                                                                   sum_h16, sum_g, sum_d, N);
    k_node<<<dim3(N / NBN), dim3(256), 0, stream>>>(h16, sum_h16, sum_g, sum_d, cnt, grid,
                                                    Wk, bk, Ww, bw, Wd1, bd1, Wd2, bd2,
                                                    out, N);
}

// Round 10
// 235.355 us; speedup vs baseline: 1.4072x; 1.4072x over previous
//
#include <hip/hip_runtime.h>
#include <hip/hip_fp16.h>

static __device__ __forceinline__ float gelu(float x) {
    return 0.5f * x * (1.0f + erff(x * 0.70710678118654752f));
}

#define NBE 64    // nodes per block, encode part
#define CAP 64    // CSR slot capacity per node

typedef _Float16 v8h __attribute__((ext_vector_type(8)));
typedef float    v4f __attribute__((ext_vector_type(4)));
union F8 { uint4 u; v8h v; _Float16 f[8]; };

static __device__ __forceinline__ void acc8(float* a, uint4 u) {
    float2 f0 = __half22float2(*(__half2*)&u.x);
    float2 f1 = __half22float2(*(__half2*)&u.y);
    float2 f2 = __half22float2(*(__half2*)&u.z);
    float2 f3 = __half22float2(*(__half2*)&u.w);
    a[0] += f0.x; a[1] += f0.y; a[2] += f1.x; a[3] += f1.y;
    a[4] += f2.x; a[5] += f2.y; a[6] += f3.x; a[7] += f3.y;
}

static __device__ __forceinline__ uint4 pack8(const float* v) {
    __half2 p0 = __floats2half2_rn(v[0], v[1]);
    __half2 p1 = __floats2half2_rn(v[2], v[3]);
    __half2 p2 = __floats2half2_rn(v[4], v[5]);
    __half2 p3 = __floats2half2_rn(v[6], v[7]);
    uint4 u;
    u.x = *(unsigned*)&p0; u.y = *(unsigned*)&p1;
    u.z = *(unsigned*)&p2; u.w = *(unsigned*)&p3;
    return u;
}

// ---- merged: encoder (blocks < encB) + slot-scatter (blocks >= encB) ----
__global__ void __launch_bounds__(256, 1)
k_enc_scat(const float* __restrict__ x,
           const float* __restrict__ grid,
           const float* __restrict__ W1,
           const float* __restrict__ b1,
           const float* __restrict__ W2,
           const float* __restrict__ b2,
           const int* __restrict__ ei, int* __restrict__ cnt,
           int* __restrict__ ssrc,
           __half* __restrict__ h16, int N, int E, int encB)
{
    __shared__ float sx[NBE * 10];
    __shared__ float sg[NBE * 2];
    __shared__ float sm[NBE * 132];
    int tid = threadIdx.x;
    if ((int)blockIdx.x >= encB) {
        int e4 = (blockIdx.x - encB) * 256 + tid;   // 4 edges per thread
        if (e4 * 4 < E) {
            const int4* s4 = (const int4*)ei;
            const int4* d4 = (const int4*)(ei + E);
            int4 s = s4[e4];
            int4 d = d4[e4];
            int p;
            p = atomicAdd(&cnt[d.x], 1); if (p < CAP) ssrc[((size_t)d.x << 6) + p] = s.x;
            p = atomicAdd(&cnt[d.y], 1); if (p < CAP) ssrc[((size_t)d.y << 6) + p] = s.y;
            p = atomicAdd(&cnt[d.z], 1); if (p < CAP) ssrc[((size_t)d.z << 6) + p] = s.z;
            p = atomicAdd(&cnt[d.w], 1); if (p < CAP) ssrc[((size_t)d.w << 6) + p] = s.w;
        }
        return;
    }
    int n0 = blockIdx.x * NBE;
    for (int i = tid; i < NBE * 10; i += 256) sx[i] = x[(size_t)n0 * 10 + i];
    if (tid < NBE * 2) sg[tid] = grid[(size_t)n0 * 2 + tid];
    __syncthreads();

    int l = tid & 7, r = tid >> 3;
    int mb = 16 * l;
    float in[2][12];
#pragma unroll
    for (int m = 0; m < 2; m++) {
        int node = r + 32 * m;
#pragma unroll
        for (int k = 0; k < 10; k++) in[m][k] = sx[node * 10 + k];
        in[m][10] = sg[node * 2 + 0];
        in[m][11] = sg[node * 2 + 1];
    }

    float macc[2][16];
#pragma unroll
    for (int i = 0; i < 16; i++) {
        float b = b1[mb + i];
        macc[0][i] = b; macc[1][i] = b;
    }
#pragma unroll
    for (int k = 0; k < 12; k++) {
        const float4* w = (const float4*)(W1 + k * 128 + mb);
#pragma unroll
        for (int q = 0; q < 4; q++) {
            float4 wv = w[q];
#pragma unroll
            for (int m = 0; m < 2; m++) {
                float xv = in[m][k];
                macc[m][4 * q + 0] += xv * wv.x;
                macc[m][4 * q + 1] += xv * wv.y;
                macc[m][4 * q + 2] += xv * wv.z;
                macc[m][4 * q + 3] += xv * wv.w;
            }
        }
    }
#pragma unroll
    for (int m = 0; m < 2; m++) {
        float4* smp = (float4*)(sm + (r + 32 * m) * 132 + mb);
#pragma unroll
        for (int q = 0; q < 4; q++)
            smp[q] = make_float4(gelu(macc[m][4 * q]), gelu(macc[m][4 * q + 1]),
                                 gelu(macc[m][4 * q + 2]), gelu(macc[m][4 * q + 3]));
    }
    __syncthreads();

    int ob = 8 * l;
    float out8[2][8];
#pragma unroll
    for (int j = 0; j < 8; j++) {
        float b = b2[ob + j];
        out8[0][j] = b; out8[1][j] = b;
    }
#pragma unroll 2
    for (int i4 = 0; i4 < 128; i4 += 4) {
        float mva[2][4];
#pragma unroll
        for (int m = 0; m < 2; m++)
            *(float4*)mva[m] = *(const float4*)&sm[(r + 32 * m) * 132 + i4];
#pragma unroll
        for (int ii = 0; ii < 4; ii++) {
            const float4* w = (const float4*)(W2 + (i4 + ii) * 64 + ob);
            float4 w0 = w[0], w1 = w[1];
#pragma unroll
            for (int m = 0; m < 2; m++) {
                float mv = mva[m][ii];
                out8[m][0] += mv * w0.x; out8[m][1] += mv * w0.y;
                out8[m][2] += mv * w0.z; out8[m][3] += mv * w0.w;
                out8[m][4] += mv * w1.x; out8[m][5] += mv * w1.y;
                out8[m][6] += mv * w1.z; out8[m][7] += mv * w1.w;
            }
        }
    }
#pragma unroll
    for (int m = 0; m < 2; m++)
        ((uint4*)(h16 + (size_t)(n0 + r + 32 * m) * 64))[l] = pack8(out8[m]);
}

// ---- gather per-node sums from CAP-slot CSR (unchanged from r9) ----
__global__ void k_gather(const __half* __restrict__ h16,
                         const float* __restrict__ grid,
                         const int* __restrict__ ssrc, const int* __restrict__ cnt,
                         __half* __restrict__ sum_h16, float* __restrict__ sum_g,
                         float* __restrict__ sum_d, int N)
{
    int tid = blockIdx.x * blockDim.x + threadIdx.x;
    int n = tid >> 3;
    int l = tid & 7;
    if (n >= N) return;
    int beg = n << 6;
    int dg = min(cnt[n], CAP);
    const uint4* h8 = (const uint4*)h16;
    float a0[8] = {0,0,0,0,0,0,0,0};
    float a1[8] = {0,0,0,0,0,0,0,0};
    float a2[8] = {0,0,0,0,0,0,0,0};
    float a3[8] = {0,0,0,0,0,0,0,0};
    float sgx = 0.f, sgy = 0.f, sd = 0.f, gix = 0.f, giy = 0.f;
    if (l == 0) { gix = grid[2 * n]; giy = grid[2 * n + 1]; }
    int i = 0;
    for (; i + 3 < dg; i += 4) {
        int4 s = *(const int4*)&ssrc[beg + i];
        uint4 u0 = h8[(size_t)s.x * 8 + l];
        uint4 u1 = h8[(size_t)s.y * 8 + l];
        uint4 u2 = h8[(size_t)s.z * 8 + l];
        uint4 u3 = h8[(size_t)s.w * 8 + l];
        acc8(a0, u0); acc8(a1, u1); acc8(a2, u2); acc8(a3, u3);
        if (l == 0) {
            float gx0 = grid[2 * s.x], gy0 = grid[2 * s.x + 1];
            float gx1 = grid[2 * s.y], gy1 = grid[2 * s.y + 1];
            float gx2 = grid[2 * s.z], gy2 = grid[2 * s.z + 1];
            float gx3 = grid[2 * s.w], gy3 = grid[2 * s.w + 1];
            float dx0 = gix - gx0, dy0 = giy - gy0;
            float dx1 = gix - gx1, dy1 = giy - gy1;
            float dx2 = gix - gx2, dy2 = giy - gy2;
            float dx3 = gix - gx3, dy3 = giy - gy3;
            sd += sqrtf(dx0 * dx0 + dy0 * dy0) + sqrtf(dx1 * dx1 + dy1 * dy1)
                + sqrtf(dx2 * dx2 + dy2 * dy2) + sqrtf(dx3 * dx3 + dy3 * dy3);
            sgx += gx0 + gx1 + gx2 + gx3;
            sgy += gy0 + gy1 + gy2 + gy3;
        }
    }
    for (; i < dg; i++) {
        int s0 = ssrc[beg + i];
        uint4 u0 = h8[(size_t)s0 * 8 + l];
        acc8(a0, u0);
        if (l == 0) {
            float gx0 = grid[2 * s0], gy0 = grid[2 * s0 + 1];
            float dx0 = gix - gx0, dy0 = giy - gy0;
            sd += sqrtf(dx0 * dx0 + dy0 * dy0);
            sgx += gx0; sgy += gy0;
        }
    }
#pragma unroll
    for (int j = 0; j < 8; j++) a0[j] += a1[j] + a2[j] + a3[j];
    ((uint4*)(sum_h16 + (size_t)n * 64))[l] = pack8(a0);
    if (l == 0) { sum_d[n] = sd; sum_g[2 * n] = sgx; sum_g[2 * n + 1] = sgy; }
}

// ---- k_update: h2 = gelu(rank1 + h@Ww + (deg*h)@WkC + sum_h@WkD) via MFMA ----
// 16-node tiles; A-frag: A[m=lane&15][k=quad*8+j] == contiguous uint4 of h16.
// B-frags (fp16) packed per block into LDS: B[k=quad*8+j][n=lane&15+16*nt].
// Rank-1 terms as extra MFMA: U=[1,deg,sd,gix,giy,sgx,sgy] x V rows.
// h2 (fp16) written into the sum_h16 buffer (read-before-write per tile).
__global__ void __launch_bounds__(256, 1)
k_update(const __half* __restrict__ h16, __half* __restrict__ sum_h16,
         const float* __restrict__ sum_g, const float* __restrict__ sum_d,
         const int* __restrict__ cnt, const float* __restrict__ grid,
         const float* __restrict__ Wk, const float* __restrict__ bk,
         const float* __restrict__ Ww, const float* __restrict__ bw, int N)
{
    __shared__ uint4 tabW[512];   // Ww  frags: idx = kc*256 + nt*64 + lane
    __shared__ uint4 tabC[512];   // WkC (Wk rows 5..68)
    __shared__ uint4 tabD[512];   // WkD (Wk rows 69..132)
    __shared__ uint4 tabV[256];   // rank-1 V frags: idx = nt*64 + lane
    int tid = threadIdx.x;

    for (int idx = tid; idx < 512; idx += 256) {
        int lane = idx & 63, nt = (idx >> 6) & 3, kc = idx >> 8;
        int col = nt * 16 + (lane & 15);
        int kr  = kc * 32 + ((lane >> 4) << 3);
        F8 fw, fc, fd;
#pragma unroll
        for (int j = 0; j < 8; j++) {
            fw.f[j] = (_Float16)Ww[(kr + j) * 64 + col];
            fc.f[j] = (_Float16)Wk[(size_t)(5 + kr + j) * 64 + col];
            fd.f[j] = (_Float16)Wk[(size_t)(69 + kr + j) * 64 + col];
        }
        tabW[idx] = fw.u; tabC[idx] = fc.u; tabD[idx] = fd.u;
    }
    if (tid < 256) {
        int lane = tid & 63, nt = tid >> 6;
        int col = nt * 16 + (lane & 15);
        F8 fv;
#pragma unroll
        for (int j = 0; j < 8; j++) fv.f[j] = (_Float16)0.f;
        if ((lane >> 4) == 0) {
            fv.f[0] = (_Float16)bw[col];
            fv.f[1] = (_Float16)bk[col];
            fv.f[2] = (_Float16)Wk[col];
            fv.f[3] = (_Float16)Wk[64 + col];
            fv.f[4] = (_Float16)Wk[128 + col];
            fv.f[5] = (_Float16)Wk[192 + col];
            fv.f[6] = (_Float16)Wk[256 + col];
        }
        tabV[tid] = fv.u;
    }
    __syncthreads();

    int lane = tid & 63, wave = tid >> 6;
    int m = lane & 15, quad = lane >> 4;
    const uint4* h8 = (const uint4*)h16;
    const uint4* s8 = (const uint4*)sum_h16;

    for (int t = 0; t < 2; t++) {
        int tile = blockIdx.x * 8 + wave * 2 + t;
        int base = tile * 16;
        int n = base + m;
        float deg = (float)cnt[n];
        float sd  = sum_d[n];
        float sgx = sum_g[2 * n], sgy = sum_g[2 * n + 1];
        float gix = grid[2 * n] * deg, giy = grid[2 * n + 1] * deg;

        // A-frags
        F8 ah0, ah1, as0, as1, ahd0, ahd1, au;
        ah0.u = h8[(size_t)n * 8 + quad];
        ah1.u = h8[(size_t)n * 8 + 4 + quad];
        as0.u = s8[(size_t)n * 8 + quad];
        as1.u = s8[(size_t)n * 8 + 4 + quad];
        _Float16 dh = (_Float16)deg;
#pragma unroll
        for (int j = 0; j < 8; j++) { ahd0.f[j] = ah0.f[j] * dh; ahd1.f[j] = ah1.f[j] * dh; }
        float z = (quad == 0) ? 1.f : 0.f;
        au.f[0] = (_Float16)z;          au.f[1] = (_Float16)(deg * z);
        au.f[2] = (_Float16)(sd * z);   au.f[3] = (_Float16)(gix * z);
        au.f[4] = (_Float16)(giy * z);  au.f[5] = (_Float16)(sgx * z);
        au.f[6] = (_Float16)(sgy * z);  au.f[7] = (_Float16)0.f;

        float h2v[4][4];
#pragma unroll
        for (int nt = 0; nt < 4; nt++) {
            F8 bv, bw0, bw1, bc0, bc1, bd0, bd1f;
            bv.u  = tabV[nt * 64 + lane];
            bw0.u = tabW[nt * 64 + lane];       bw1.u = tabW[256 + nt * 64 + lane];
            bc0.u = tabC[nt * 64 + lane];       bc1.u = tabC[256 + nt * 64 + lane];
            bd0.u = tabD[nt * 64 + lane];       bd1f.u = tabD[256 + nt * 64 + lane];
            v4f acc = {0.f, 0.f, 0.f, 0.f};
            acc = __builtin_amdgcn_mfma_f32_16x16x32_f16(au.v,   bv.v,   acc, 0, 0, 0);
            acc = __builtin_amdgcn_mfma_f32_16x16x32_f16(ah0.v,  bw0.v,  acc, 0, 0, 0);
            acc = __builtin_amdgcn_mfma_f32_16x16x32_f16(ah1.v,  bw1.v,  acc, 0, 0, 0);
            acc = __builtin_amdgcn_mfma_f32_16x16x32_f16(ahd0.v, bc0.v,  acc, 0, 0, 0);
            acc = __builtin_amdgcn_mfma_f32_16x16x32_f16(ahd1.v, bc1.v,  acc, 0, 0, 0);
            acc = __builtin_amdgcn_mfma_f32_16x16x32_f16(as0.v,  bd0.v,  acc, 0, 0, 0);
            acc = __builtin_amdgcn_mfma_f32_16x16x32_f16(as1.v,  bd1f.v, acc, 0, 0, 0);
#pragma unroll
            for (int reg = 0; reg < 4; reg++) h2v[nt][reg] = gelu(acc[reg]);
        }
        // D layout: row m' = quad*4+reg, col = m + 16*nt. Write h2 into sum_h16.
#pragma unroll
        for (int reg = 0; reg < 4; reg++) {
            int nr = base + quad * 4 + reg;
#pragma unroll
            for (int nt = 0; nt < 4; nt++)
                sum_h16[(size_t)nr * 64 + m + 16 * nt] = __float2half(h2v[nt][reg]);
        }
    }
}

// ---- k_decode: out = gelu(h2@Wd1+bd1)@Wd2 + bd2 via MFMA ----
__global__ void __launch_bounds__(256, 1)
k_decode(const __half* __restrict__ h2g,
         const float* __restrict__ Wd1, const float* __restrict__ bd1,
         const float* __restrict__ Wd2, const float* __restrict__ bd2,
         float* __restrict__ out, int N)
{
    __shared__ uint4 tab[1024];   // Wd1 frags: idx = kc*512 + nt*64 + lane
    int tid = threadIdx.x;
    for (int idx = tid; idx < 1024; idx += 256) {
        int lane = idx & 63, nt = (idx >> 6) & 7, kc = idx >> 9;
        int col = nt * 16 + (lane & 15);
        int kr  = kc * 32 + ((lane >> 4) << 3);
        F8 f;
#pragma unroll
        for (int j = 0; j < 8; j++) f.f[j] = (_Float16)Wd1[(kr + j) * 128 + col];
        tab[idx] = f.u;
    }
    __syncthreads();

    int lane = tid & 63, wave = tid >> 6;
    int m = lane & 15, quad = lane >> 4;
    const uint4* h8 = (const uint4*)h2g;
    float bd2v = bd2[0];

    for (int t = 0; t < 2; t++) {
        int tile = blockIdx.x * 8 + wave * 2 + t;
        int base = tile * 16;
        int n = base + m;
        F8 ah0, ah1;
        ah0.u = h8[(size_t)n * 8 + quad];
        ah1.u = h8[(size_t)n * 8 + 4 + quad];
        float p[4] = {0.f, 0.f, 0.f, 0.f};
#pragma unroll
        for (int nt = 0; nt < 8; nt++) {
            int col = m + 16 * nt;
            float b = bd1[col];
            float w2 = Wd2[col];
            F8 b0, b1;
            b0.u = tab[nt * 64 + lane];
            b1.u = tab[512 + nt * 64 + lane];
            v4f acc = {b, b, b, b};
            acc = __builtin_amdgcn_mfma_f32_16x16x32_f16(ah0.v, b0.v, acc, 0, 0, 0);
            acc = __builtin_amdgcn_mfma_f32_16x16x32_f16(ah1.v, b1.v, acc, 0, 0, 0);
#pragma unroll
            for (int reg = 0; reg < 4; reg++) p[reg] += gelu(acc[reg]) * w2;
        }
#pragma unroll
        for (int reg = 0; reg < 4; reg++) {
            p[reg] += __shfl_xor(p[reg], 1);
            p[reg] += __shfl_xor(p[reg], 2);
            p[reg] += __shfl_xor(p[reg], 4);
            p[reg] += __shfl_xor(p[reg], 8);
        }
        if (m == 0) {
#pragma unroll
            for (int reg = 0; reg < 4; reg++)
                out[base + quad * 4 + reg] = p[reg] + bd2v;
        }
    }
}

extern "C" void kernel_launch(void* const* d_in, const int* in_sizes, int n_in,
                              void* d_out, int out_size, void* d_ws, size_t ws_size,
                              hipStream_t stream)
{
    const float* x    = (const float*)d_in[0];
    const float* grid = (const float*)d_in[1];
    const int*   ei   = (const int*)d_in[2];
    const float* W1   = (const float*)d_in[3];
    const float* b1   = (const float*)d_in[4];
    const float* W2   = (const float*)d_in[5];
    const float* b2   = (const float*)d_in[6];
    const float* Wk   = (const float*)d_in[7];
    const float* bk   = (const float*)d_in[8];
    const float* Ww   = (const float*)d_in[9];
    const float* bw   = (const float*)d_in[10];
    const float* Wd1  = (const float*)d_in[11];
    const float* bd1  = (const float*)d_in[12];
    const float* Wd2  = (const float*)d_in[13];
    const float* bd2  = (const float*)d_in[14];
    float* out = (float*)d_out;

    int N = in_sizes[0] / 10;
    int E = in_sizes[2] / 2;

    char* ws = (char*)d_ws;
    size_t o_h16  = 0;
    size_t o_sh16 = o_h16  + (size_t)N * 64 * 2;
    size_t o_sumg = o_sh16 + (size_t)N * 64 * 2;
    size_t o_sumd = o_sumg + (size_t)N * 2 * 4;
    size_t o_cnt  = o_sumd + (size_t)N * 4;
    size_t o_ssrc = o_cnt  + (size_t)N * 4;

    __half* h16     = (__half*)(ws + o_h16);
    __half* sum_h16 = (__half*)(ws + o_sh16);   // reused as h2 after k_update
    float* sum_g = (float*)(ws + o_sumg);
    float* sum_d = (float*)(ws + o_sumd);
    int*   cnt   = (int*)  (ws + o_cnt);
    int*   ssrc  = (int*)  (ws + o_ssrc);   // N * CAP ints

    hipMemsetAsync(cnt, 0, (size_t)N * 4, stream);

    int encB  = N / NBE;                 // 1024
    int scatB = (E / 4 + 255) / 256;     // 1024
    k_enc_scat<<<dim3(encB + scatB), dim3(256), 0, stream>>>(x, grid, W1, b1, W2, b2,
                                                             ei, cnt, ssrc, h16, N, E, encB);
    k_gather<<<dim3((N * 8 + 255) / 256), dim3(256), 0, stream>>>(h16, grid, ssrc, cnt,
                                                                   sum_h16, sum_g, sum_d, N);
    int tiles = N / 16;                  // 4096
    k_update<<<dim3(tiles / 8), dim3(256), 0, stream>>>(h16, sum_h16, sum_g, sum_d, cnt,
                                                        grid, Wk, bk, Ww, bw, N);
    k_decode<<<dim3(tiles / 8), dim3(256), 0, stream>>>(sum_h16, Wd1, bd1, Wd2, bd2, out, N);
}